// Round 1
// baseline (305.380 us; speedup 1.0000x reference)
//
#include <hip/hip_runtime.h>

// FFF tree-routed feedforward: B=65536, nIn=nOut=1024, DEPTH=10, n_nodes=1023.
// One 64-lane wave per sample. Each lane owns 16 elements (4x float4) of the
// 1024-dim vectors: chunk c covers elements c*256 + lane*4 .. +3 (coalesced
// 1KB per vector load instruction).

#define FFF_DEPTH 10
#define N_IN 1024
#define N_OUT 1024

__global__ __launch_bounds__(256) void fff_kernel(
    const float* __restrict__ x,
    const float* __restrict__ w1s,
    const float* __restrict__ w2s,
    float* __restrict__ y,
    int B)
{
    const int lane = threadIdx.x & 63;
    const int wave = threadIdx.x >> 6;
    const int b = blockIdx.x * 4 + wave;
    if (b >= B) return;

    // Load this sample's x into registers (16 floats/lane).
    const float4* x4 = reinterpret_cast<const float4*>(x + (size_t)b * N_IN);
    float4 xv[4];
    #pragma unroll
    for (int c = 0; c < 4; ++c) xv[c] = x4[c * 64 + lane];

    float4 acc[4];
    #pragma unroll
    for (int c = 0; c < 4; ++c) acc[c] = make_float4(0.f, 0.f, 0.f, 0.f);

    int node = 0;
    #pragma unroll
    for (int d = 0; d < FFF_DEPTH; ++d) {
        // node is wave-uniform -> scalar base addresses.
        const float4* w1 = reinterpret_cast<const float4*>(w1s + (size_t)node * N_IN);
        const float4* w2 = reinterpret_cast<const float4*>(w2s + (size_t)node * N_OUT);
        float4 w1v[4], w2v[4];
        #pragma unroll
        for (int c = 0; c < 4; ++c) {
            w1v[c] = w1[c * 64 + lane];
            w2v[c] = w2[c * 64 + lane];   // issued early; consumed after reduce
        }
        // Per-lane partial dot (16 FMAs).
        float p = 0.f;
        #pragma unroll
        for (int c = 0; c < 4; ++c) {
            p += xv[c].x * w1v[c].x;
            p += xv[c].y * w1v[c].y;
            p += xv[c].z * w1v[c].z;
            p += xv[c].w * w1v[c].w;
        }
        // 64-lane butterfly reduce; all lanes end with the full dot.
        #pragma unroll
        for (int m = 32; m >= 1; m >>= 1) p += __shfl_xor(p, m, 64);

        // Accumulate lam * w2s[node] (off the critical routing chain).
        #pragma unroll
        for (int c = 0; c < 4; ++c) {
            acc[c].x += p * w2v[c].x;
            acc[c].y += p * w2v[c].y;
            acc[c].z += p * w2v[c].z;
            acc[c].w += p * w2v[c].w;
        }
        // Descend: node = 2*node + 1 + (lam > 0)
        node = node * 2 + 1 + (p > 0.f ? 1 : 0);
        node = __builtin_amdgcn_readfirstlane(node);
    }

    float4* y4 = reinterpret_cast<float4*>(y + (size_t)b * N_OUT);
    #pragma unroll
    for (int c = 0; c < 4; ++c) y4[c * 64 + lane] = acc[c];
}

extern "C" void kernel_launch(void* const* d_in, const int* in_sizes, int n_in,
                              void* d_out, int out_size, void* d_ws, size_t ws_size,
                              hipStream_t stream) {
    const float* x   = (const float*)d_in[0];
    const float* w1s = (const float*)d_in[1];
    const float* w2s = (const float*)d_in[2];
    float* y = (float*)d_out;
    const int B = in_sizes[0] / N_IN;      // 65536
    const int blocks = (B + 3) / 4;        // 4 samples (waves) per 256-thread block
    fff_kernel<<<blocks, 256, 0, stream>>>(x, w1s, w2s, y, B);
}

// Round 2
// 287.007 us; speedup vs baseline: 1.0640x; 1.0640x over previous
//
#include <hip/hip_runtime.h>

// FFF tree-routed feedforward: B=65536, nIn=nOut=1024, DEPTH=10, n_nodes=1023.
// One 64-lane wave per sample; lane owns 16 elems (4x float4), coalesced.
// Phase 1: route 10 levels (w1 gather + DPP wave-reduce). Phase 2: replay the
// 10 (node, lam) pairs against w2 with fully independent, pipelineable loads.
// x (read-once) and y (write-once) use non-temporal ops so they don't thrash
// the LLC that the 8 MB weight set needs to stay resident in.

#define FFF_DEPTH 10
#define N_IN 1024
#define N_OUT 1024

typedef float f32x4 __attribute__((ext_vector_type(4)));

// v += dpp_mov(v, CTRL); control codes: 0x111..0x118 = row_shr 1/2/4/8,
// 0x142 = row_bcast15 (rows 1,3), 0x143 = row_bcast31 (rows 2,3).
template<int CTRL, int ROW_MASK>
__device__ __forceinline__ float dpp_add(float v) {
    int sh = __builtin_amdgcn_update_dpp(0, __builtin_bit_cast(int, v),
                                         CTRL, ROW_MASK, 0xf, true);
    return v + __builtin_bit_cast(float, sh);
}

__global__ __launch_bounds__(256) void fff_kernel(
    const float* __restrict__ x,
    const float* __restrict__ w1s,
    const float* __restrict__ w2s,
    float* __restrict__ y,
    int B)
{
    const int lane = threadIdx.x & 63;
    const int wv = threadIdx.x >> 6;
    const int b = blockIdx.x * 4 + wv;
    if (b >= B) return;

    // x: read exactly once -> non-temporal (don't pollute LLC).
    const f32x4* x4 = reinterpret_cast<const f32x4*>(x + (size_t)b * N_IN);
    f32x4 xv[4];
    #pragma unroll
    for (int c = 0; c < 4; ++c) xv[c] = __builtin_nontemporal_load(&x4[c * 64 + lane]);

    // ---- Phase 1: routing (w1 only) ----
    int nodes[FFF_DEPTH];
    float lams[FFF_DEPTH];
    int node = 0;
    #pragma unroll
    for (int d = 0; d < FFF_DEPTH; ++d) {
        const f32x4* w1 = reinterpret_cast<const f32x4*>(w1s + (size_t)node * N_IN);
        f32x4 w[4];
        #pragma unroll
        for (int c = 0; c < 4; ++c) w[c] = w1[c * 64 + lane];

        float p0 = 0.f, p1 = 0.f, p2 = 0.f, p3 = 0.f;   // 4 independent chains
        #pragma unroll
        for (int c = 0; c < 4; ++c) {
            p0 += xv[c][0] * w[c][0];
            p1 += xv[c][1] * w[c][1];
            p2 += xv[c][2] * w[c][2];
            p3 += xv[c][3] * w[c][3];
        }
        float p = (p0 + p1) + (p2 + p3);

        // 64-lane sum via DPP (VALU pipe, ~12 ops) instead of 6x ds_permute.
        p = dpp_add<0x111, 0xf>(p);   // row_shr:1
        p = dpp_add<0x112, 0xf>(p);   // row_shr:2
        p = dpp_add<0x114, 0xf>(p);   // row_shr:4
        p = dpp_add<0x118, 0xf>(p);   // row_shr:8  -> lane15 of each row = row sum
        p = dpp_add<0x142, 0xa>(p);   // row_bcast15 -> lane31: rows0+1, lane63: rows2+3
        p = dpp_add<0x143, 0xc>(p);   // row_bcast31 -> lane63: total
        float lam = __builtin_bit_cast(float,
            __builtin_amdgcn_readlane(__builtin_bit_cast(int, p), 63));  // SGPR broadcast

        nodes[d] = node;
        lams[d] = lam;
        node = node * 2 + 1 + (lam > 0.f ? 1 : 0);
    }

    // ---- Phase 2: y = sum_d lams[d] * w2s[nodes[d]] ----
    // Fully unrolled: 40 independent loads, compiler pipelines them deeply.
    f32x4 acc[4];
    #pragma unroll
    for (int c = 0; c < 4; ++c) acc[c] = (f32x4)0.f;

    #pragma unroll
    for (int d = 0; d < FFF_DEPTH; ++d) {
        const f32x4* w2 = reinterpret_cast<const f32x4*>(w2s + (size_t)nodes[d] * N_OUT);
        const float lam = lams[d];
        #pragma unroll
        for (int c = 0; c < 4; ++c) {
            f32x4 w = w2[c * 64 + lane];
            acc[c] += lam * w;
        }
    }

    // y: written exactly once -> non-temporal store.
    f32x4* y4 = reinterpret_cast<f32x4*>(y + (size_t)b * N_OUT);
    #pragma unroll
    for (int c = 0; c < 4; ++c) __builtin_nontemporal_store(acc[c], &y4[c * 64 + lane]);
}

extern "C" void kernel_launch(void* const* d_in, const int* in_sizes, int n_in,
                              void* d_out, int out_size, void* d_ws, size_t ws_size,
                              hipStream_t stream) {
    const float* x   = (const float*)d_in[0];
    const float* w1s = (const float*)d_in[1];
    const float* w2s = (const float*)d_in[2];
    float* y = (float*)d_out;
    const int B = in_sizes[0] / N_IN;      // 65536
    const int blocks = (B + 3) / 4;        // 4 waves (samples) per 256-thread block
    fff_kernel<<<blocks, 256, 0, stream>>>(x, w1s, w2s, y, B);
}